// Round 1
// baseline (28910.898 us; speedup 1.0000x reference)
//
#include <hip/hip_runtime.h>
#include <math.h>

#define B_   64
#define N_   512
#define L_   12
#define H_   12
#define RNN  64
#define MEMN 20
#define MEMD 64
#define DD   128          // decoder hidden
#define CENC 65           // encoder cat channels (1 + 64)
#define CDEC 134          // decoder cat channels (1 + 5 + 128)
#define NB   (N_*B_)      // 32768

// ---------------- generic fp32 tiled GEMM: C = A(M,K) @ B(K,N) [+C] ----------------
#define TS 64
#define KT 16

__global__ __launch_bounds__(256)
void gemm_f32(const float* __restrict__ A, int lda,
              const float* __restrict__ Bm, int ldb,
              float* __restrict__ C, int ldc,
              int M, int N, int K, int beta, int epi) {
  __shared__ __align__(16) float As[KT][TS + 4];   // [k][m], +4 pad keeps 16B align
  __shared__ __align__(16) float Bs[KT][TS + 4];   // [k][n]
  const int tx = threadIdx.x & 15, ty = threadIdx.x >> 4;
  const int bm = blockIdx.y * TS, bn = blockIdx.x * TS;
  float acc[4][4] = {};
  for (int k0 = 0; k0 < K; k0 += KT) {
    for (int t = threadIdx.x; t < TS * KT; t += 256) {
      int i = t >> 4, kk = t & 15;                 // A tile: row i (m), col kk (k)
      int row = bm + i, col = k0 + kk;
      As[kk][i] = (row < M && col < K) ? A[(size_t)row * lda + col] : 0.f;
    }
    for (int t = threadIdx.x; t < KT * TS; t += 256) {
      int kk = t >> 6, j = t & 63;                 // B tile: row kk (k), col j (n)
      int row = k0 + kk, col = bn + j;
      Bs[kk][j] = (row < K && col < N) ? Bm[(size_t)row * ldb + col] : 0.f;
    }
    __syncthreads();
#pragma unroll
    for (int kk = 0; kk < KT; kk++) {
      float4 a4 = *reinterpret_cast<const float4*>(&As[kk][ty * 4]);
      float4 b4 = *reinterpret_cast<const float4*>(&Bs[kk][tx * 4]);
      float a[4] = {a4.x, a4.y, a4.z, a4.w};
      float b[4] = {b4.x, b4.y, b4.z, b4.w};
#pragma unroll
      for (int i = 0; i < 4; i++)
#pragma unroll
        for (int j = 0; j < 4; j++) acc[i][j] += a[i] * b[j];
    }
    __syncthreads();
  }
#pragma unroll
  for (int i = 0; i < 4; i++) {
    int row = bm + ty * 4 + i;
    if (row >= M) continue;
#pragma unroll
    for (int j = 0; j < 4; j++) {
      int col = bn + tx * 4 + j;
      if (col >= N) continue;
      float v = acc[i][j];
      if (epi == 1) v = 2.f * v - (row == col ? 1.f : 0.f);   // Chebyshev 2*G@G - I
      size_t o = (size_t)row * ldc + col;
      C[o] = beta ? C[o] + v : v;
    }
  }
}

// ---------------- small kernels ----------------
__global__ void fill_zero(float* p, int n) {
  int i = blockIdx.x * 256 + threadIdx.x;
  if (i < n) p[i] = 0.f;
}

__global__ void scores_relu(const float* __restrict__ e1, const float* __restrict__ e2,
                            float* __restrict__ S) {
  int idx = blockIdx.x * 256 + threadIdx.x;
  if (idx >= N_ * N_) return;
  int n = idx >> 9, m = idx & 511;
  float s = 0.f;
  for (int k = 0; k < MEMD; k++) s += e1[n * MEMD + k] * e2[m * MEMD + k];
  S[idx] = s > 0.f ? s : 0.f;
}

__global__ __launch_bounds__(256)
void row_softmax(const float* __restrict__ S, float* __restrict__ G, int trans) {
  int r = blockIdx.x;
  __shared__ float red[256];
  float m = -1e30f;
  for (int j = threadIdx.x; j < N_; j += 256) {
    float v = trans ? S[j * N_ + r] : S[r * N_ + j];
    m = fmaxf(m, v);
  }
  red[threadIdx.x] = m; __syncthreads();
  for (int s = 128; s > 0; s >>= 1) {
    if (threadIdx.x < s) red[threadIdx.x] = fmaxf(red[threadIdx.x], red[threadIdx.x + s]);
    __syncthreads();
  }
  m = red[0]; __syncthreads();
  float sum = 0.f;
  for (int j = threadIdx.x; j < N_; j += 256) {
    float v = trans ? S[j * N_ + r] : S[r * N_ + j];
    sum += expf(v - m);
  }
  red[threadIdx.x] = sum; __syncthreads();
  for (int s = 128; s > 0; s >>= 1) {
    if (threadIdx.x < s) red[threadIdx.x] += red[threadIdx.x + s];
    __syncthreads();
  }
  float inv = 1.f / red[0];
  for (int j = threadIdx.x; j < N_; j += 256) {
    float v = trans ? S[j * N_ + r] : S[r * N_ + j];
    G[r * N_ + j] = expf(v - m) * inv;
  }
}

// Wsum = W[block0] + W[block3]  (the two identity-support blocks)
__global__ void add_blocks(const float* __restrict__ W, float* __restrict__ Wsum, int C, int O) {
  int idx = blockIdx.x * 256 + threadIdx.x;
  if (idx >= C * O) return;
  Wsum[idx] = W[idx] + W[3 * C * O + idx];
}

// X2 layout (N, B*C): element [n][b*C+c]; r = n*B + b
__global__ void build_enc_x(float* __restrict__ X2, const float* __restrict__ x,
                            const float* __restrict__ Hb, const float* __restrict__ ZR, int t) {
  int e = blockIdx.x * 256 + threadIdx.x;
  if (e >= NB * CENC) return;
  int r = e / CENC, c = e % CENC;
  float v;
  if (c == 0) {
    int n = r >> 6, b = r & 63;
    v = x[b * (N_ * L_) + n * L_ + t];        // x: (B,1,N,L)
  } else {
    int ch = c - 1;
    v = Hb[r * RNN + ch];
    if (ZR) v *= ZR[r * (2 * RNN) + ch];      // z * h
  }
  X2[e] = v;
}

__global__ void build_dec_x(float* __restrict__ X2, const float* __restrict__ go,
                            const float* __restrict__ tt, const float* __restrict__ Hd,
                            const float* __restrict__ ZR, int t) {
  int e = blockIdx.x * 256 + threadIdx.x;
  if (e >= NB * CDEC) return;
  int r = e / CDEC, c = e % CDEC;
  int b = r & 63;
  float v;
  if (c == 0) v = go[r];
  else if (c < 6) v = tt[b * (5 * H_) + (c - 1) * H_ + t];   // targets_time: (B,5,1,H)
  else {
    int ch = c - 6;
    v = Hd[r * DD + ch];
    if (ZR) v *= ZR[r * (2 * DD) + ch];
  }
  X2[e] = v;
}

__global__ void bias_act(float* __restrict__ X, const float* __restrict__ bias,
                         int total, int cols, int mode) {
  int e = blockIdx.x * 256 + threadIdx.x;
  if (e >= total) return;
  int c = e % cols;
  float v = X[e] + bias[c];
  X[e] = (mode == 0) ? 1.f / (1.f + expf(-v)) : tanhf(v);
}

__global__ void h_update(float* __restrict__ Hb, const float* __restrict__ ZR,
                         const float* __restrict__ HC, int hd) {
  int e = blockIdx.x * 256 + threadIdx.x;
  if (e >= NB * hd) return;
  int r = e / hd, c = e % hd;
  float rr = ZR[r * 2 * hd + hd + c];
  Hb[e] = rr * Hb[e] + (1.f - rr) * HC[e];
}

__global__ __launch_bounds__(64)
void attention(const float* __restrict__ Hb, const float* __restrict__ Wq,
               const float* __restrict__ Mem, float* __restrict__ Hde) {
  int r = blockIdx.x, t = threadIdx.x;
  __shared__ float hrow[RNN], q[MEMD], sc[MEMN];
  hrow[t] = Hb[r * RNN + t];
  __syncthreads();
  float a = 0.f;
  for (int k = 0; k < RNN; k++) a += hrow[k] * Wq[k * MEMD + t];
  q[t] = a;
  __syncthreads();
  if (t < MEMN) {
    float s = 0.f;
    for (int c = 0; c < MEMD; c++) s += q[c] * Mem[t * MEMD + c];
    sc[t] = s;
  }
  __syncthreads();
  if (t == 0) {
    float m = -1e30f;
    for (int j = 0; j < MEMN; j++) m = fmaxf(m, sc[j]);
    float ssum = 0.f;
    for (int j = 0; j < MEMN; j++) { sc[j] = expf(sc[j] - m); ssum += sc[j]; }
    float inv = 1.f / ssum;
    for (int j = 0; j < MEMN; j++) sc[j] *= inv;
  }
  __syncthreads();
  float ha = 0.f;
  for (int j = 0; j < MEMN; j++) ha += sc[j] * Mem[j * MEMD + t];
  Hde[r * DD + t] = hrow[t];
  Hde[r * DD + RNN + t] = ha;
}

__global__ void dec_out(const float* __restrict__ Hd, const float* __restrict__ pW,
                        const float* __restrict__ pb, float* __restrict__ out,
                        float* __restrict__ go, int t) {
  int r = blockIdx.x * 256 + threadIdx.x;
  if (r >= NB) return;
  float s = pb[0];
  for (int c = 0; c < DD; c++) s += Hd[r * DD + c] * pW[c];
  go[r] = s;
  int n = r >> 6, b = r & 63;
  out[b * (N_ * H_) + n * H_ + t] = s;   // out: (B,1,N,H)
}

// ---------------- host orchestration ----------------
extern "C" void kernel_launch(void* const* d_in, const int* in_sizes, int n_in,
                              void* d_out, int out_size, void* d_ws, size_t ws_size,
                              hipStream_t stream) {
  const float* x   = (const float*)d_in[0];
  const float* tt  = (const float*)d_in[3];
  const float* Mem = (const float*)d_in[5];
  const float* Wq  = (const float*)d_in[6];
  const float* We1 = (const float*)d_in[7];
  const float* We2 = (const float*)d_in[8];
  const float* egW = (const float*)d_in[9];
  const float* egb = (const float*)d_in[10];
  const float* euW = (const float*)d_in[11];
  const float* eub = (const float*)d_in[12];
  const float* dgW = (const float*)d_in[13];
  const float* dgb = (const float*)d_in[14];
  const float* duW = (const float*)d_in[15];
  const float* dub = (const float*)d_in[16];
  const float* pW  = (const float*)d_in[17];
  const float* pb  = (const float*)d_in[18];
  float* out = (float*)d_out;

  float* ws = (float*)d_ws;
  size_t off = 0;
  auto alloc = [&](size_t n) { float* p = ws + off; off += n; return p; };
  float* e1    = alloc(N_ * MEMD);
  float* e2    = alloc(N_ * MEMD);
  float* S     = alloc(N_ * N_);
  float* g1    = alloc(N_ * N_);
  float* g2    = alloc(N_ * N_);
  float* G1    = alloc(N_ * N_);
  float* G2    = alloc(N_ * N_);
  float* egW03 = alloc(CENC * 2 * RNN);
  float* euW03 = alloc(CENC * RNN);
  float* dgW03 = alloc(CDEC * 2 * DD);
  float* duW03 = alloc(CDEC * DD);
  float* Hb    = alloc(NB * RNN);     // encoder h, layout (N,B,64)
  float* Hd    = alloc(NB * DD);      // decoder h, layout (N,B,128)
  float* X2    = alloc(NB * CDEC);    // cat buffer, layout (N, B*C)
  float* Y     = alloc(NB * CDEC);    // graph-mix temp
  float* ZR    = alloc(NB * 2 * DD);  // gate output
  float* HC    = alloc(NB * DD);      // candidate
  float* GO    = alloc(NB);           // decoder go, layout (N,B)

  auto gemm = [&](const float* A, int lda, const float* Bm, int ldb, float* C, int ldc,
                  int M, int Nn, int K, int beta, int epi) {
    dim3 g((Nn + TS - 1) / TS, (M + TS - 1) / TS);
    gemm_f32<<<g, 256, 0, stream>>>(A, lda, Bm, ldb, C, ldc, M, Nn, K, beta, epi);
  };
  auto blk = [](int n) { return dim3((n + 255) / 256); };

  // ---- Phase 0: memory graph + supports (once per call) ----
  gemm(We1, MEMN, Mem, MEMD, e1, MEMD, N_, MEMD, MEMN, 0, 0);
  gemm(We2, MEMN, Mem, MEMD, e2, MEMD, N_, MEMD, MEMN, 0, 0);
  scores_relu<<<blk(N_ * N_), 256, 0, stream>>>(e1, e2, S);
  row_softmax<<<N_, 256, 0, stream>>>(S, g1, 0);
  row_softmax<<<N_, 256, 0, stream>>>(S, g2, 1);
  gemm(g1, N_, g1, N_, G1, N_, N_, N_, N_, 0, 1);   // 2*g1@g1 - I
  gemm(g2, N_, g2, N_, G2, N_, N_, N_, N_, 0, 1);
  add_blocks<<<blk(CENC * 2 * RNN), 256, 0, stream>>>(egW, egW03, CENC, 2 * RNN);
  add_blocks<<<blk(CENC * RNN), 256, 0, stream>>>(euW, euW03, CENC, RNN);
  add_blocks<<<blk(CDEC * 2 * DD), 256, 0, stream>>>(dgW, dgW03, CDEC, 2 * DD);
  add_blocks<<<blk(CDEC * DD), 256, 0, stream>>>(duW, duW03, CDEC, DD);
  fill_zero<<<blk(NB * RNN), 256, 0, stream>>>(Hb, NB * RNN);

  const float* P[4] = {g1, G1, g2, G2};
  const int blkrow[4] = {1, 2, 4, 5};   // W block index for each non-identity support

  // agcn: outbuf(NB,O) = sum_blocks (S_k @ X)flat @ W_k  (identity blocks pre-summed)
  auto agcn = [&](float* Xin, int C, const float* W, const float* Wsum03, int O, float* outbuf) {
    gemm(Xin, C, Wsum03, O, outbuf, O, NB, O, C, 0, 0);           // identity blocks
    for (int s = 0; s < 4; s++) {
      gemm(P[s], N_, Xin, B_ * C, Y, B_ * C, N_, B_ * C, N_, 0, 0);  // Y = P_s @ X
      gemm(Y, C, W + blkrow[s] * C * O, O, outbuf, O, NB, O, C, 1, 0);
    }
  };

  // ---- Encoder ----
  for (int t = 0; t < L_; t++) {
    build_enc_x<<<blk(NB * CENC), 256, 0, stream>>>(X2, x, Hb, nullptr, t);
    agcn(X2, CENC, egW, egW03, 2 * RNN, ZR);
    bias_act<<<blk(NB * 2 * RNN), 256, 0, stream>>>(ZR, egb, NB * 2 * RNN, 2 * RNN, 0);
    build_enc_x<<<blk(NB * CENC), 256, 0, stream>>>(X2, x, Hb, ZR, t);
    agcn(X2, CENC, euW, euW03, RNN, HC);
    bias_act<<<blk(NB * RNN), 256, 0, stream>>>(HC, eub, NB * RNN, RNN, 1);
    h_update<<<blk(NB * RNN), 256, 0, stream>>>(Hb, ZR, HC, RNN);
  }

  // ---- Attention + h_de ----
  attention<<<NB, 64, 0, stream>>>(Hb, Wq, Mem, Hd);
  fill_zero<<<blk(NB), 256, 0, stream>>>(GO, NB);

  // ---- Decoder ----
  for (int t = 0; t < H_; t++) {
    build_dec_x<<<blk(NB * CDEC), 256, 0, stream>>>(X2, GO, tt, Hd, nullptr, t);
    agcn(X2, CDEC, dgW, dgW03, 2 * DD, ZR);
    bias_act<<<blk(NB * 2 * DD), 256, 0, stream>>>(ZR, dgb, NB * 2 * DD, 2 * DD, 0);
    build_dec_x<<<blk(NB * CDEC), 256, 0, stream>>>(X2, GO, tt, Hd, ZR, t);
    agcn(X2, CDEC, duW, duW03, DD, HC);
    bias_act<<<blk(NB * DD), 256, 0, stream>>>(HC, dub, NB * DD, DD, 1);
    h_update<<<blk(NB * DD), 256, 0, stream>>>(Hd, ZR, HC, DD);
    dec_out<<<blk(NB), 256, 0, stream>>>(Hd, pW, pb, out, GO, t);
  }
}

// Round 3
// 4749.245 us; speedup vs baseline: 6.0875x; 6.0875x over previous
//
#include <hip/hip_runtime.h>
#include <hip/hip_bf16.h>
#include <math.h>

typedef __hip_bfloat16 bf16;
typedef __attribute__((ext_vector_type(8))) short s8v;
typedef __attribute__((ext_vector_type(4))) float f4v;

#define B_   64
#define N_   512
#define L_   12
#define H_   12
#define RNN  64
#define MEMN 20
#define MEMD 64
#define DD   128
#define NB   32768          // N_*B_ ; r = b*512 + n (b-major)

// ---------- global->LDS 16B DMA (dest = wave-uniform base + lane*16) ----------
__device__ inline void glds16(const bf16* g, bf16* l) {
  __builtin_amdgcn_global_load_lds((const __attribute__((address_space(1))) void*)g,
                                   (__attribute__((address_space(3))) void*)l, 16, 0, 0);
}

// =================== MFMA GEMM 1: graph mix ===================
// Y_s = S_s @ X.  A = Sb (2048x512 bf16 row-major, rows=(s,node)),
// B^T = XT ((b*C+c) x 512 bf16 row-major). Out: Yb[s][(b*512+nn)*CP + c] bf16.
template<int C_CH, int CP>
__global__ __launch_bounds__(256) void gemm_mix(
    const bf16* __restrict__ Sb, const bf16* __restrict__ XT, bf16* __restrict__ Yb) {
  const int NCOLS = 64 * C_CH;
  __shared__ bf16 As[128 * 32];
  __shared__ bf16 Bs[128 * 32];
  const int tid = threadIdx.x, lane = tid & 63, wid = tid >> 6;
  const int wr = wid >> 1, wc = wid & 1;
  const int bm = blockIdx.y * 128, bn = blockIdx.x * 128;
  const int r_in = lane >> 2, dslot = lane & 3;
  f4v acc[4][4] = {};
  for (int k0 = 0; k0 < 512; k0 += 32) {
#pragma unroll
    for (int h = 0; h < 2; h++) {
      int ci = wid + h * 4;
      int row = ci * 16 + r_in;
      int ss = dslot ^ ((row >> 1) & 3);             // source-side swizzle
      glds16(Sb + (size_t)(bm + row) * 512 + k0 + ss * 8, As + ci * 512);
      glds16(XT + (size_t)(bn + row) * 512 + k0 + ss * 8, Bs + ci * 512);
    }
    asm volatile("s_waitcnt vmcnt(0)" ::: "memory");
    __syncthreads();
    s8v a[4], bb[4];
#pragma unroll
    for (int m = 0; m < 4; m++) {
      int row = wr * 64 + m * 16 + (lane & 15);
      int slot = (lane >> 4) ^ ((row >> 1) & 3);     // matching read swizzle
      a[m] = *(const s8v*)(As + row * 32 + slot * 8);
    }
#pragma unroll
    for (int n = 0; n < 4; n++) {
      int col = wc * 64 + n * 16 + (lane & 15);
      int slot = (lane >> 4) ^ ((col >> 1) & 3);
      bb[n] = *(const s8v*)(Bs + col * 32 + slot * 8);
    }
#pragma unroll
    for (int m = 0; m < 4; m++)
#pragma unroll
      for (int n = 0; n < 4; n++)
        acc[m][n] = __builtin_amdgcn_mfma_f32_16x16x32_bf16(a[m], bb[n], acc[m][n], 0, 0, 0);
    __syncthreads();
  }
#pragma unroll
  for (int m = 0; m < 4; m++) {
#pragma unroll
    for (int rg = 0; rg < 4; rg++) {
      int row = bm + wr * 64 + m * 16 + (lane >> 4) * 4 + rg;
      int s = row >> 9, nn = row & 511;
      size_t obase = (size_t)s * NB * CP;
#pragma unroll
      for (int n = 0; n < 4; n++) {
        int col = bn + wc * 64 + n * 16 + (lane & 15);
        if (col < NCOLS) {
          int b = col / C_CH, c = col - b * C_CH;
          Yb[obase + (size_t)(b * 512 + nn) * CP + c] = __float2bfloat16(acc[m][n][rg]);
        }
      }
    }
  }
}

// =================== MFMA GEMM 2: projection (transposed) ===================
// Z^T[o][r] = sum_seg sum_c WT[seg][o][c] * Bseg[r][c];  Bseg r-major, c-contiguous.
// seg 0 -> XC (the concat input, r-major stride CP, pads zeroed);
// segs 1..4 -> Yb (mix outputs). EPI 0: ZRT[o*NB+r] = sigmoid(acc+bias[o]).
// EPI 1 (o<hd): hc=tanh(acc+bias[o]); rr=ZRT[(hd+o)*NB+r]; HT=rr*HT+(1-rr)*hc.
template<int CP, int EPI>
__global__ __launch_bounds__(256) void gemm_proj(
    const bf16* __restrict__ WT, const bf16* __restrict__ XC,
    const bf16* __restrict__ Yb, const float* __restrict__ bias,
    float* __restrict__ ZRT, float* __restrict__ HT, int hd) {
  __shared__ bf16 As[128 * 32];
  __shared__ bf16 Bs[128 * 32];
  const int tid = threadIdx.x, lane = tid & 63, wid = tid >> 6;
  const int wr = wid >> 1, wc = wid & 1;
  const int bm = blockIdx.y * 128, bn = blockIdx.x * 128;
  const int Opad = gridDim.y * 128;
  const int r_in = lane >> 2, dslot = lane & 3;
  f4v acc[4][4] = {};
  for (int seg = 0; seg < 5; seg++) {
    const bf16* Bbase = (seg == 0) ? XC : (Yb + (size_t)(seg - 1) * NB * CP);
    const bf16* Abase = WT + (size_t)seg * Opad * CP;
    for (int k0 = 0; k0 < CP; k0 += 32) {
#pragma unroll
      for (int h = 0; h < 2; h++) {
        int ci = wid + h * 4;
        int row = ci * 16 + r_in;
        int ss = dslot ^ ((row >> 1) & 3);
        glds16(Abase + (size_t)(bm + row) * CP + k0 + ss * 8, As + ci * 512);
        glds16(Bbase + (size_t)(bn + row) * CP + k0 + ss * 8, Bs + ci * 512);
      }
      asm volatile("s_waitcnt vmcnt(0)" ::: "memory");
      __syncthreads();
      s8v a[4], bb[4];
#pragma unroll
      for (int m = 0; m < 4; m++) {
        int row = wr * 64 + m * 16 + (lane & 15);
        int slot = (lane >> 4) ^ ((row >> 1) & 3);
        a[m] = *(const s8v*)(As + row * 32 + slot * 8);
      }
#pragma unroll
      for (int n = 0; n < 4; n++) {
        int col = wc * 64 + n * 16 + (lane & 15);
        int slot = (lane >> 4) ^ ((col >> 1) & 3);
        bb[n] = *(const s8v*)(Bs + col * 32 + slot * 8);
      }
#pragma unroll
      for (int m = 0; m < 4; m++)
#pragma unroll
        for (int n = 0; n < 4; n++)
          acc[m][n] = __builtin_amdgcn_mfma_f32_16x16x32_bf16(a[m], bb[n], acc[m][n], 0, 0, 0);
      __syncthreads();
    }
  }
#pragma unroll
  for (int m = 0; m < 4; m++) {
#pragma unroll
    for (int rg = 0; rg < 4; rg++) {
      int o = bm + wr * 64 + m * 16 + (lane >> 4) * 4 + rg;
#pragma unroll
      for (int n = 0; n < 4; n++) {
        int r = bn + wc * 64 + n * 16 + (lane & 15);
        float v = acc[m][n][rg];
        if (EPI == 0) {
          v += bias[o];
          ZRT[(size_t)o * NB + r] = 1.f / (1.f + expf(-v));
        } else {
          if (o < hd) {
            v = tanhf(v + bias[o]);
            float rr = ZRT[(size_t)(hd + o) * NB + r];
            float* hp = HT + (size_t)o * NB + r;
            *hp = rr * (*hp) + (1.f - rr) * v;
          }
        }
      }
    }
  }
}

// ---------------- fp32 GEMM (phase-0 small/one-off) ----------------
#define TS 64
#define KT 16
__global__ __launch_bounds__(256)
void gemm_f32(const float* __restrict__ A, int lda,
              const float* __restrict__ Bm, int ldb,
              float* __restrict__ C, int ldc,
              int M, int N, int K, int epi) {
  __shared__ __align__(16) float Asf[KT][TS + 4];
  __shared__ __align__(16) float Bsf[KT][TS + 4];
  const int tx = threadIdx.x & 15, ty = threadIdx.x >> 4;
  const int bm = blockIdx.y * TS, bn = blockIdx.x * TS;
  float acc[4][4] = {};
  for (int k0 = 0; k0 < K; k0 += KT) {
    for (int t = threadIdx.x; t < TS * KT; t += 256) {
      int i = t >> 4, kk = t & 15;
      int row = bm + i, col = k0 + kk;
      Asf[kk][i] = (row < M && col < K) ? A[(size_t)row * lda + col] : 0.f;
    }
    for (int t = threadIdx.x; t < KT * TS; t += 256) {
      int kk = t >> 6, j = t & 63;
      int row = k0 + kk, col = bn + j;
      Bsf[kk][j] = (row < K && col < N) ? Bm[(size_t)row * ldb + col] : 0.f;
    }
    __syncthreads();
#pragma unroll
    for (int kk = 0; kk < KT; kk++) {
      float4 a4 = *reinterpret_cast<const float4*>(&Asf[kk][ty * 4]);
      float4 b4 = *reinterpret_cast<const float4*>(&Bsf[kk][tx * 4]);
      float a[4] = {a4.x, a4.y, a4.z, a4.w};
      float b[4] = {b4.x, b4.y, b4.z, b4.w};
#pragma unroll
      for (int i = 0; i < 4; i++)
#pragma unroll
        for (int j = 0; j < 4; j++) acc[i][j] += a[i] * b[j];
    }
    __syncthreads();
  }
#pragma unroll
  for (int i = 0; i < 4; i++) {
    int row = bm + ty * 4 + i;
    if (row >= M) continue;
#pragma unroll
    for (int j = 0; j < 4; j++) {
      int col = bn + tx * 4 + j;
      if (col >= N) continue;
      float v = acc[i][j];
      if (epi == 1) v = 2.f * v - (row == col ? 1.f : 0.f);
      C[(size_t)row * ldc + col] = v;
    }
  }
}

// ---------------- small kernels ----------------
__global__ void fill_zero4(float4* p, int n) {
  for (int i = blockIdx.x * 256 + threadIdx.x; i < n; i += gridDim.x * 256)
    p[i] = make_float4(0.f, 0.f, 0.f, 0.f);
}

__global__ void fill_ybuf_pads(bf16* Yb) {   // zero dec-stride pads c in [134,160)
  int idx = blockIdx.x * 256 + threadIdx.x;
  if (idx >= 4 * NB * 26) return;
  int s = idx / (NB * 26);
  int rem = idx - s * (NB * 26);
  int r = rem / 26, c = 134 + (rem - (rem / 26) * 26);
  Yb[(size_t)s * NB * 160 + (size_t)r * 160 + c] = __float2bfloat16(0.f);
}

__global__ void scores_relu(const float* __restrict__ e1, const float* __restrict__ e2,
                            float* __restrict__ S) {
  int idx = blockIdx.x * 256 + threadIdx.x;
  if (idx >= N_ * N_) return;
  int n = idx >> 9, m = idx & 511;
  float s = 0.f;
  for (int k = 0; k < MEMD; k++) s += e1[n * MEMD + k] * e2[m * MEMD + k];
  S[idx] = s > 0.f ? s : 0.f;
}

__global__ __launch_bounds__(256)
void row_softmax(const float* __restrict__ S, float* __restrict__ G, int trans) {
  int r = blockIdx.x;
  __shared__ float red[256];
  float m = -1e30f;
  for (int j = threadIdx.x; j < N_; j += 256) {
    float v = trans ? S[j * N_ + r] : S[r * N_ + j];
    m = fmaxf(m, v);
  }
  red[threadIdx.x] = m; __syncthreads();
  for (int s = 128; s > 0; s >>= 1) {
    if (threadIdx.x < s) red[threadIdx.x] = fmaxf(red[threadIdx.x], red[threadIdx.x + s]);
    __syncthreads();
  }
  m = red[0]; __syncthreads();
  float sum = 0.f;
  for (int j = threadIdx.x; j < N_; j += 256) {
    float v = trans ? S[j * N_ + r] : S[r * N_ + j];
    sum += expf(v - m);
  }
  red[threadIdx.x] = sum; __syncthreads();
  for (int s = 128; s > 0; s >>= 1) {
    if (threadIdx.x < s) red[threadIdx.x] += red[threadIdx.x + s];
    __syncthreads();
  }
  float inv = 1.f / red[0];
  for (int j = threadIdx.x; j < N_; j += 256) {
    float v = trans ? S[j * N_ + r] : S[r * N_ + j];
    G[r * N_ + j] = expf(v - m) * inv;
  }
}

__global__ void f32_to_bf16(const float* __restrict__ src, bf16* __restrict__ dst, int n) {
  int i = blockIdx.x * 256 + threadIdx.x;
  if (i < n) dst[i] = __float2bfloat16(src[i]);
}

// WT[seg][Opad][CP]; seg0 = blocks 0+3 (identity supports), segs 1..4 = blocks {1,2,4,5}
__global__ void prep_wt(const float* __restrict__ W, bf16* __restrict__ WT,
                        int C, int O, int Opad, int CP) {
  int idx = blockIdx.x * 256 + threadIdx.x;
  int tot = 5 * Opad * CP;
  if (idx >= tot) return;
  int seg = idx / (Opad * CP);
  int rem = idx - seg * (Opad * CP);
  int o = rem / CP, c = rem - (rem / CP) * CP;
  float v = 0.f;
  if (c < C && o < O) {
    const int blkmap[5] = {0, 1, 2, 4, 5};
    int blk = blkmap[seg];
    v = W[(blk * C + c) * O + o];
    if (seg == 0) v += W[(3 * C + c) * O + o];
  }
  WT[idx] = __float2bfloat16(v);
}

// ---- builds: XT[(b*C+c)*512 + n], XC[r*CP + c] (r = b*512+n), both bf16 ----
__global__ void build_xt_enc(bf16* __restrict__ XT, const float* __restrict__ x,
                             const float* __restrict__ HT, const float* __restrict__ ZRT, int t) {
  int idx = blockIdx.x * 256 + threadIdx.x;
  if (idx >= 4160 * 512) return;
  int row = idx >> 9, n = idx & 511;
  int b = row / 65, c = row - b * 65;
  int r = b * 512 + n;
  float v;
  if (c == 0) v = x[b * 6144 + n * 12 + t];
  else {
    v = HT[(size_t)(c - 1) * NB + r];
    if (ZRT) v *= ZRT[(size_t)(c - 1) * NB + r];
  }
  XT[idx] = __float2bfloat16(v);
}

__global__ void build_xc_enc(bf16* __restrict__ XC, const float* __restrict__ x,
                             const float* __restrict__ HT, const float* __restrict__ ZRT, int t) {
  int idx = blockIdx.x * 256 + threadIdx.x;
  if (idx >= NB * 96) return;
  int r = idx / 96, c = idx - r * 96;
  float v = 0.f;
  if (c == 0) {
    int b = r >> 9, n = r & 511;
    v = x[b * 6144 + n * 12 + t];
  } else if (c < 65) {
    v = HT[(size_t)(c - 1) * NB + r];
    if (ZRT) v *= ZRT[(size_t)(c - 1) * NB + r];
  }
  XC[idx] = __float2bfloat16(v);
}

__global__ void build_xt_dec(bf16* __restrict__ XT, const float* __restrict__ GO,
                             const float* __restrict__ tt, const float* __restrict__ HT,
                             const float* __restrict__ ZRT, int t) {
  int idx = blockIdx.x * 256 + threadIdx.x;
  if (idx >= 8576 * 512) return;
  int row = idx >> 9, n = idx & 511;
  int b = row / 134, c = row - b * 134;
  int r = b * 512 + n;
  float v;
  if (c == 0) v = GO[r];
  else if (c < 6) v = tt[b * 60 + (c - 1) * 12 + t];
  else {
    v = HT[(size_t)(c - 6) * NB + r];
    if (ZRT) v *= ZRT[(size_t)(c - 6) * NB + r];
  }
  XT[idx] = __float2bfloat16(v);
}

__global__ void build_xc_dec(bf16* __restrict__ XC, const float* __restrict__ GO,
                             const float* __restrict__ tt, const float* __restrict__ HT,
                             const float* __restrict__ ZRT, int t) {
  int idx = blockIdx.x * 256 + threadIdx.x;
  if (idx >= NB * 160) return;
  int r = idx / 160, c = idx - r * 160;
  int b = r >> 9;
  float v = 0.f;
  if (c == 0) v = GO[r];
  else if (c < 6) v = tt[b * 60 + (c - 1) * 12 + t];
  else if (c < 134) {
    v = HT[(size_t)(c - 6) * NB + r];
    if (ZRT) v *= ZRT[(size_t)(c - 6) * NB + r];
  }
  XC[idx] = __float2bfloat16(v);
}

__global__ __launch_bounds__(64)
void attention(const float* __restrict__ HbT, const float* __restrict__ Wq,
               const float* __restrict__ Mem, float* __restrict__ HdT) {
  int r = blockIdx.x, t = threadIdx.x;
  __shared__ float hrow[RNN], q[MEMD], sc[MEMN];
  hrow[t] = HbT[(size_t)t * NB + r];
  __syncthreads();
  float a = 0.f;
  for (int k = 0; k < RNN; k++) a += hrow[k] * Wq[k * MEMD + t];
  q[t] = a;
  __syncthreads();
  if (t < MEMN) {
    float s = 0.f;
    for (int c = 0; c < MEMD; c++) s += q[c] * Mem[t * MEMD + c];
    sc[t] = s;
  }
  __syncthreads();
  if (t == 0) {
    float m = -1e30f;
    for (int j = 0; j < MEMN; j++) m = fmaxf(m, sc[j]);
    float ssum = 0.f;
    for (int j = 0; j < MEMN; j++) { sc[j] = expf(sc[j] - m); ssum += sc[j]; }
    float inv = 1.f / ssum;
    for (int j = 0; j < MEMN; j++) sc[j] *= inv;
  }
  __syncthreads();
  float ha = 0.f;
  for (int j = 0; j < MEMN; j++) ha += sc[j] * Mem[j * MEMD + t];
  HdT[(size_t)t * NB + r] = hrow[t];
  HdT[(size_t)(RNN + t) * NB + r] = ha;
}

__global__ void dec_out(const float* __restrict__ HdT, const float* __restrict__ pW,
                        const float* __restrict__ pb, float* __restrict__ out,
                        float* __restrict__ GO, int t) {
  int r = blockIdx.x * 256 + threadIdx.x;
  if (r >= NB) return;
  float s = pb[0];
  for (int c = 0; c < DD; c++) s += HdT[(size_t)c * NB + r] * pW[c];
  GO[r] = s;
  int b = r >> 9, n = r & 511;
  out[b * 6144 + n * 12 + t] = s;
}

// ---------------- host ----------------
extern "C" void kernel_launch(void* const* d_in, const int* in_sizes, int n_in,
                              void* d_out, int out_size, void* d_ws, size_t ws_size,
                              hipStream_t stream) {
  const float* x   = (const float*)d_in[0];
  const float* tt  = (const float*)d_in[3];
  const float* Mem = (const float*)d_in[5];
  const float* Wq  = (const float*)d_in[6];
  const float* We1 = (const float*)d_in[7];
  const float* We2 = (const float*)d_in[8];
  const float* egW = (const float*)d_in[9];
  const float* egb = (const float*)d_in[10];
  const float* euW = (const float*)d_in[11];
  const float* eub = (const float*)d_in[12];
  const float* dgW = (const float*)d_in[13];
  const float* dgb = (const float*)d_in[14];
  const float* duW = (const float*)d_in[15];
  const float* dub = (const float*)d_in[16];
  const float* pW  = (const float*)d_in[17];
  const float* pb  = (const float*)d_in[18];
  float* out = (float*)d_out;

  char* ws = (char*)d_ws;
  size_t off = 0;
  auto alloc = [&](size_t bytes) { char* p = ws + off; off += (bytes + 255) & ~(size_t)255; return p; };
  // ---- zeroed-at-launch-start region (contiguous) ----
  bf16* XC    = (bf16*)alloc((size_t)NB * 160 * 2);        // [r*CP + c]
  bf16* Ybuf  = (bf16*)alloc((size_t)4 * NB * 160 * 2);    // [s][r*CP + c]
  float* HbT  = (float*)alloc((size_t)RNN * NB * 4);       // [o][r]
  float* GO   = (float*)alloc((size_t)NB * 4);
  size_t zero_bytes = off;
  // ---- rest ----
  bf16* WTeg  = (bf16*)alloc((size_t)5 * 128 * 96 * 2);
  bf16* WTeu  = (bf16*)alloc((size_t)5 * 128 * 96 * 2);
  bf16* WTdg  = (bf16*)alloc((size_t)5 * 256 * 160 * 2);
  bf16* WTdu  = (bf16*)alloc((size_t)5 * 128 * 160 * 2);
  bf16* XT    = (bf16*)alloc((size_t)8576 * 512 * 2);      // [(b*C+c)][n]
  bf16* Sb    = (bf16*)alloc((size_t)4 * 512 * 512 * 2);
  float* ZRT  = (float*)alloc((size_t)256 * NB * 4);       // [o][r]
  float* HdT  = (float*)alloc((size_t)DD * NB * 4);
  float* e1   = (float*)alloc((size_t)N_ * MEMD * 4);
  float* e2   = (float*)alloc((size_t)N_ * MEMD * 4);
  float* S    = (float*)alloc((size_t)N_ * N_ * 4);
  float* g1   = (float*)alloc((size_t)N_ * N_ * 4);
  float* g2   = (float*)alloc((size_t)N_ * N_ * 4);
  float* G1   = (float*)alloc((size_t)N_ * N_ * 4);
  float* G2   = (float*)alloc((size_t)N_ * N_ * 4);

  auto blk = [](long n) { return dim3((unsigned)((n + 255) / 256)); };
  auto gemmf = [&](const float* A, int lda, const float* Bm, int ldb, float* C, int ldc,
                   int M, int Nn, int K, int epi) {
    dim3 g((Nn + TS - 1) / TS, (M + TS - 1) / TS);
    gemm_f32<<<g, 256, 0, stream>>>(A, lda, Bm, ldb, C, ldc, M, Nn, K, epi);
  };

  // phase 0
  fill_zero4<<<2048, 256, 0, stream>>>((float4*)ws, (int)(zero_bytes / 16));
  gemmf(We1, MEMN, Mem, MEMD, e1, MEMD, N_, MEMD, MEMN, 0);
  gemmf(We2, MEMN, Mem, MEMD, e2, MEMD, N_, MEMD, MEMN, 0);
  scores_relu<<<blk(N_ * N_), 256, 0, stream>>>(e1, e2, S);
  row_softmax<<<N_, 256, 0, stream>>>(S, g1, 0);
  row_softmax<<<N_, 256, 0, stream>>>(S, g2, 1);
  gemmf(g1, N_, g1, N_, G1, N_, N_, N_, N_, 1);
  gemmf(g2, N_, g2, N_, G2, N_, N_, N_, N_, 1);
  f32_to_bf16<<<blk(262144), 256, 0, stream>>>(g1, Sb + 0 * 262144, 262144);
  f32_to_bf16<<<blk(262144), 256, 0, stream>>>(G1, Sb + 1 * 262144, 262144);
  f32_to_bf16<<<blk(262144), 256, 0, stream>>>(g2, Sb + 2 * 262144, 262144);
  f32_to_bf16<<<blk(262144), 256, 0, stream>>>(G2, Sb + 3 * 262144, 262144);
  prep_wt<<<blk(5 * 128 * 96), 256, 0, stream>>>(egW, WTeg, 65, 128, 128, 96);
  prep_wt<<<blk(5 * 128 * 96), 256, 0, stream>>>(euW, WTeu, 65, 64, 128, 96);
  prep_wt<<<blk(5 * 256 * 160), 256, 0, stream>>>(dgW, WTdg, 134, 256, 256, 160);
  prep_wt<<<blk(5 * 128 * 160), 256, 0, stream>>>(duW, WTdu, 134, 128, 128, 160);

  // encoder
  for (int t = 0; t < L_; t++) {
    build_xt_enc<<<blk((long)4160 * 512), 256, 0, stream>>>(XT, x, HbT, nullptr, t);
    build_xc_enc<<<blk((long)NB * 96), 256, 0, stream>>>(XC, x, HbT, nullptr, t);
    gemm_mix<65, 96><<<dim3(33, 16), 256, 0, stream>>>(Sb, XT, Ybuf);
    gemm_proj<96, 0><<<dim3(256, 1), 256, 0, stream>>>(WTeg, XC, Ybuf, egb, ZRT, nullptr, RNN);
    build_xt_enc<<<blk((long)4160 * 512), 256, 0, stream>>>(XT, x, HbT, ZRT, t);
    build_xc_enc<<<blk((long)NB * 96), 256, 0, stream>>>(XC, x, HbT, ZRT, t);
    gemm_mix<65, 96><<<dim3(33, 16), 256, 0, stream>>>(Sb, XT, Ybuf);
    gemm_proj<96, 1><<<dim3(256, 1), 256, 0, stream>>>(WTeu, XC, Ybuf, eub, ZRT, HbT, RNN);
  }

  // attention -> HdT ; dec-stride pads
  attention<<<dim3(NB), 64, 0, stream>>>(HbT, Wq, Mem, HdT);
  fill_ybuf_pads<<<blk((long)4 * NB * 26), 256, 0, stream>>>(Ybuf);

  // decoder
  for (int t = 0; t < H_; t++) {
    build_xt_dec<<<blk((long)8576 * 512), 256, 0, stream>>>(XT, GO, tt, HdT, nullptr, t);
    build_xc_dec<<<blk((long)NB * 160), 256, 0, stream>>>(XC, GO, tt, HdT, nullptr, t);
    gemm_mix<134, 160><<<dim3(67, 16), 256, 0, stream>>>(Sb, XT, Ybuf);
    gemm_proj<160, 0><<<dim3(256, 2), 256, 0, stream>>>(WTdg, XC, Ybuf, dgb, ZRT, nullptr, DD);
    build_xt_dec<<<blk((long)8576 * 512), 256, 0, stream>>>(XT, GO, tt, HdT, ZRT, t);
    build_xc_dec<<<blk((long)NB * 160), 256, 0, stream>>>(XC, GO, tt, HdT, ZRT, t);
    gemm_mix<134, 160><<<dim3(67, 16), 256, 0, stream>>>(Sb, XT, Ybuf);
    gemm_proj<160, 1><<<dim3(256, 1), 256, 0, stream>>>(WTdu, XC, Ybuf, dub, ZRT, HdT, DD);
    dec_out<<<blk(NB), 256, 0, stream>>>(HdT, pW, pb, out, GO, t);
  }
}

// Round 4
// 3799.630 us; speedup vs baseline: 7.6089x; 1.2499x over previous
//
#include <hip/hip_runtime.h>
#include <hip/hip_bf16.h>
#include <math.h>

typedef __hip_bfloat16 bf16;
typedef __attribute__((ext_vector_type(8))) short s8v;
typedef __attribute__((ext_vector_type(4))) float f4v;

#define B_   64
#define N_   512
#define L_   12
#define H_   12
#define RNN  64
#define MEMN 20
#define MEMD 64
#define DD   128
#define NB   32768          // N_*B_ ; r = b*512 + n (b-major)

// ---------- global->LDS 16B DMA (dest = wave-uniform base + lane*16) ----------
__device__ inline void glds16(const bf16* g, bf16* l) {
  __builtin_amdgcn_global_load_lds((const __attribute__((address_space(1))) void*)g,
                                   (__attribute__((address_space(3))) void*)l, 16, 0, 0);
}

// =================== MFMA GEMM 1: graph mix ===================
// Y_s = S_s @ X.  A = Sb (2048x512 bf16 row-major, rows=(s,node)),
// B^T = XT ((b*C+c) x 512 bf16 row-major). Out: Yb[s][(b*512+nn)*CP + c] bf16.
template<int C_CH, int CP>
__global__ __launch_bounds__(256) void gemm_mix(
    const bf16* __restrict__ Sb, const bf16* __restrict__ XT, bf16* __restrict__ Yb) {
  const int NCOLS = 64 * C_CH;
  __shared__ bf16 As[128 * 32];
  __shared__ bf16 Bs[128 * 32];
  const int tid = threadIdx.x, lane = tid & 63, wid = tid >> 6;
  const int wr = wid >> 1, wc = wid & 1;
  const int bm = blockIdx.y * 128, bn = blockIdx.x * 128;
  const int r_in = lane >> 2, dslot = lane & 3;
  f4v acc[4][4] = {};
  for (int k0 = 0; k0 < 512; k0 += 32) {
#pragma unroll
    for (int h = 0; h < 2; h++) {
      int ci = wid + h * 4;
      int row = ci * 16 + r_in;
      int ss = dslot ^ ((row >> 1) & 3);             // source-side swizzle
      glds16(Sb + (size_t)(bm + row) * 512 + k0 + ss * 8, As + ci * 512);
      glds16(XT + (size_t)(bn + row) * 512 + k0 + ss * 8, Bs + ci * 512);
    }
    asm volatile("s_waitcnt vmcnt(0)" ::: "memory");
    __syncthreads();
    s8v a[4], bb[4];
#pragma unroll
    for (int m = 0; m < 4; m++) {
      int row = wr * 64 + m * 16 + (lane & 15);
      int slot = (lane >> 4) ^ ((row >> 1) & 3);     // matching read swizzle
      a[m] = *(const s8v*)(As + row * 32 + slot * 8);
    }
#pragma unroll
    for (int n = 0; n < 4; n++) {
      int col = wc * 64 + n * 16 + (lane & 15);
      int slot = (lane >> 4) ^ ((col >> 1) & 3);
      bb[n] = *(const s8v*)(Bs + col * 32 + slot * 8);
    }
#pragma unroll
    for (int m = 0; m < 4; m++)
#pragma unroll
      for (int n = 0; n < 4; n++)
        acc[m][n] = __builtin_amdgcn_mfma_f32_16x16x32_bf16(a[m], bb[n], acc[m][n], 0, 0, 0);
    __syncthreads();
  }
#pragma unroll
  for (int m = 0; m < 4; m++) {
#pragma unroll
    for (int rg = 0; rg < 4; rg++) {
      int row = bm + wr * 64 + m * 16 + (lane >> 4) * 4 + rg;
      int s = row >> 9, nn = row & 511;
      size_t obase = (size_t)s * NB * CP;
#pragma unroll
      for (int n = 0; n < 4; n++) {
        int col = bn + wc * 64 + n * 16 + (lane & 15);
        if (col < NCOLS) {
          int b = col / C_CH, c = col - b * C_CH;
          Yb[obase + (size_t)(b * 512 + nn) * CP + c] = __float2bfloat16(acc[m][n][rg]);
        }
      }
    }
  }
}

// =================== MFMA GEMM 2: projection (transposed) ===================
template<int CP, int EPI>
__global__ __launch_bounds__(256) void gemm_proj(
    const bf16* __restrict__ WT, const bf16* __restrict__ XC,
    const bf16* __restrict__ Yb, const float* __restrict__ bias,
    float* __restrict__ ZRT, float* __restrict__ HT, int hd) {
  __shared__ bf16 As[128 * 32];
  __shared__ bf16 Bs[128 * 32];
  const int tid = threadIdx.x, lane = tid & 63, wid = tid >> 6;
  const int wr = wid >> 1, wc = wid & 1;
  const int bm = blockIdx.y * 128, bn = blockIdx.x * 128;
  const int Opad = gridDim.y * 128;
  const int r_in = lane >> 2, dslot = lane & 3;
  f4v acc[4][4] = {};
  for (int seg = 0; seg < 5; seg++) {
    const bf16* Bbase = (seg == 0) ? XC : (Yb + (size_t)(seg - 1) * NB * CP);
    const bf16* Abase = WT + (size_t)seg * Opad * CP;
    for (int k0 = 0; k0 < CP; k0 += 32) {
#pragma unroll
      for (int h = 0; h < 2; h++) {
        int ci = wid + h * 4;
        int row = ci * 16 + r_in;
        int ss = dslot ^ ((row >> 1) & 3);
        glds16(Abase + (size_t)(bm + row) * CP + k0 + ss * 8, As + ci * 512);
        glds16(Bbase + (size_t)(bn + row) * CP + k0 + ss * 8, Bs + ci * 512);
      }
      asm volatile("s_waitcnt vmcnt(0)" ::: "memory");
      __syncthreads();
      s8v a[4], bb[4];
#pragma unroll
      for (int m = 0; m < 4; m++) {
        int row = wr * 64 + m * 16 + (lane & 15);
        int slot = (lane >> 4) ^ ((row >> 1) & 3);
        a[m] = *(const s8v*)(As + row * 32 + slot * 8);
      }
#pragma unroll
      for (int n = 0; n < 4; n++) {
        int col = wc * 64 + n * 16 + (lane & 15);
        int slot = (lane >> 4) ^ ((col >> 1) & 3);
        bb[n] = *(const s8v*)(Bs + col * 32 + slot * 8);
      }
#pragma unroll
      for (int m = 0; m < 4; m++)
#pragma unroll
        for (int n = 0; n < 4; n++)
          acc[m][n] = __builtin_amdgcn_mfma_f32_16x16x32_bf16(a[m], bb[n], acc[m][n], 0, 0, 0);
      __syncthreads();
    }
  }
#pragma unroll
  for (int m = 0; m < 4; m++) {
#pragma unroll
    for (int rg = 0; rg < 4; rg++) {
      int o = bm + wr * 64 + m * 16 + (lane >> 4) * 4 + rg;
#pragma unroll
      for (int n = 0; n < 4; n++) {
        int r = bn + wc * 64 + n * 16 + (lane & 15);
        float v = acc[m][n][rg];
        if (EPI == 0) {
          v += bias[o];
          ZRT[(size_t)o * NB + r] = 1.f / (1.f + expf(-v));
        } else {
          if (o < hd) {
            v = tanhf(v + bias[o]);
            float rr = ZRT[(size_t)(hd + o) * NB + r];
            float* hp = HT + (size_t)o * NB + r;
            *hp = rr * (*hp) + (1.f - rr) * v;
          }
        }
      }
    }
  }
}

// =================== MFMA Chebyshev: O = 2*A@B - I (512^3, bf16 out) ===========
__global__ __launch_bounds__(256) void gemm_cheb(
    const bf16* __restrict__ A, const bf16* __restrict__ BT, bf16* __restrict__ O) {
  __shared__ bf16 As[128 * 32];
  __shared__ bf16 Bs[128 * 32];
  const int tid = threadIdx.x, lane = tid & 63, wid = tid >> 6;
  const int wr = wid >> 1, wc = wid & 1;
  const int bm = blockIdx.y * 128, bn = blockIdx.x * 128;
  const int r_in = lane >> 2, dslot = lane & 3;
  f4v acc[4][4] = {};
  for (int k0 = 0; k0 < 512; k0 += 32) {
#pragma unroll
    for (int h = 0; h < 2; h++) {
      int ci = wid + h * 4;
      int row = ci * 16 + r_in;
      int ss = dslot ^ ((row >> 1) & 3);
      glds16(A + (size_t)(bm + row) * 512 + k0 + ss * 8, As + ci * 512);
      glds16(BT + (size_t)(bn + row) * 512 + k0 + ss * 8, Bs + ci * 512);
    }
    asm volatile("s_waitcnt vmcnt(0)" ::: "memory");
    __syncthreads();
    s8v a[4], bb[4];
#pragma unroll
    for (int m = 0; m < 4; m++) {
      int row = wr * 64 + m * 16 + (lane & 15);
      int slot = (lane >> 4) ^ ((row >> 1) & 3);
      a[m] = *(const s8v*)(As + row * 32 + slot * 8);
    }
#pragma unroll
    for (int n = 0; n < 4; n++) {
      int col = wc * 64 + n * 16 + (lane & 15);
      int slot = (lane >> 4) ^ ((col >> 1) & 3);
      bb[n] = *(const s8v*)(Bs + col * 32 + slot * 8);
    }
#pragma unroll
    for (int m = 0; m < 4; m++)
#pragma unroll
      for (int n = 0; n < 4; n++)
        acc[m][n] = __builtin_amdgcn_mfma_f32_16x16x32_bf16(a[m], bb[n], acc[m][n], 0, 0, 0);
    __syncthreads();
  }
#pragma unroll
  for (int m = 0; m < 4; m++) {
#pragma unroll
    for (int rg = 0; rg < 4; rg++) {
      int row = bm + wr * 64 + m * 16 + (lane >> 4) * 4 + rg;
#pragma unroll
      for (int n = 0; n < 4; n++) {
        int col = bn + wc * 64 + n * 16 + (lane & 15);
        float v = 2.f * acc[m][n][rg] - (row == col ? 1.f : 0.f);
        O[(size_t)row * 512 + col] = __float2bfloat16(v);
      }
    }
  }
}

// ---------------- small kernels ----------------
__global__ void fill_zero4(float4* p, int n) {
  for (int i = blockIdx.x * 256 + threadIdx.x; i < n; i += gridDim.x * 256)
    p[i] = make_float4(0.f, 0.f, 0.f, 0.f);
}

__global__ void fill_ybuf_pads(bf16* Yb) {   // zero dec-stride pads c in [134,160)
  int idx = blockIdx.x * 256 + threadIdx.x;
  if (idx >= 4 * NB * 26) return;
  int s = idx / (NB * 26);
  int rem = idx - s * (NB * 26);
  int r = rem / 26, c = 134 + (rem - (rem / 26) * 26);
  Yb[(size_t)s * NB * 160 + (size_t)r * 160 + c] = __float2bfloat16(0.f);
}

// e1/e2 = We @ Mem :  (512x20)@(20x64)
__global__ void compute_e(const float* __restrict__ We1, const float* __restrict__ We2,
                          const float* __restrict__ Mem, float* __restrict__ e1,
                          float* __restrict__ e2) {
  int idx = blockIdx.x * 256 + threadIdx.x;
  if (idx >= N_ * MEMD) return;
  int n = idx >> 6, d = idx & 63;
  float s1 = 0.f, s2 = 0.f;
  for (int k = 0; k < MEMN; k++) {
    float m = Mem[k * MEMD + d];
    s1 += We1[n * MEMN + k] * m;
    s2 += We2[n * MEMN + k] * m;
  }
  e1[idx] = s1; e2[idx] = s2;
}

__global__ void scores_relu(const float* __restrict__ e1, const float* __restrict__ e2,
                            float* __restrict__ S) {
  int idx = blockIdx.x * 256 + threadIdx.x;
  if (idx >= N_ * N_) return;
  int n = idx >> 9, m = idx & 511;
  float s = 0.f;
  for (int k = 0; k < MEMD; k++) s += e1[n * MEMD + k] * e2[m * MEMD + k];
  S[idx] = s > 0.f ? s : 0.f;
}

__global__ __launch_bounds__(256)
void row_softmax(const float* __restrict__ S, float* __restrict__ G) {
  int r = blockIdx.x;
  __shared__ float red[256];
  float m = -1e30f;
  for (int j = threadIdx.x; j < N_; j += 256) m = fmaxf(m, S[r * N_ + j]);
  red[threadIdx.x] = m; __syncthreads();
  for (int s = 128; s > 0; s >>= 1) {
    if (threadIdx.x < s) red[threadIdx.x] = fmaxf(red[threadIdx.x], red[threadIdx.x + s]);
    __syncthreads();
  }
  m = red[0]; __syncthreads();
  float sum = 0.f;
  for (int j = threadIdx.x; j < N_; j += 256) sum += expf(S[r * N_ + j] - m);
  red[threadIdx.x] = sum; __syncthreads();
  for (int s = 128; s > 0; s >>= 1) {
    if (threadIdx.x < s) red[threadIdx.x] += red[threadIdx.x + s];
    __syncthreads();
  }
  float inv = 1.f / red[0];
  for (int j = threadIdx.x; j < N_; j += 256)
    G[r * N_ + j] = expf(S[r * N_ + j] - m) * inv;
}

__global__ void trans_f32(const float* __restrict__ in, float* __restrict__ outT) {
  __shared__ float t[32][33];
  int bx = blockIdx.x * 32, by = blockIdx.y * 32;
  int x = threadIdx.x, y = threadIdx.y;           // block (32,8)
  for (int i = 0; i < 32; i += 8) t[y + i][x] = in[(by + y + i) * 512 + bx + x];
  __syncthreads();
  for (int i = 0; i < 32; i += 8) outT[(bx + y + i) * 512 + by + x] = t[x][y + i];
}

// bf16 copy + bf16 transpose of a 512x512 fp32 matrix
__global__ void trans_to_bf16(const float* __restrict__ in, bf16* __restrict__ outN,
                              bf16* __restrict__ outT) {
  __shared__ float t[32][33];
  int bx = blockIdx.x * 32, by = blockIdx.y * 32;
  int x = threadIdx.x, y = threadIdx.y;           // block (32,8)
  for (int i = 0; i < 32; i += 8) {
    float v = in[(by + y + i) * 512 + bx + x];
    t[y + i][x] = v;
    outN[(by + y + i) * 512 + bx + x] = __float2bfloat16(v);
  }
  __syncthreads();
  for (int i = 0; i < 32; i += 8)
    outT[(bx + y + i) * 512 + by + x] = __float2bfloat16(t[x][y + i]);
}

// WT[seg][Opad][CP]; seg0 = blocks 0+3 (identity supports), segs 1..4 = blocks {1,2,4,5}
__global__ void prep_wt(const float* __restrict__ W, bf16* __restrict__ WT,
                        int C, int O, int Opad, int CP) {
  int idx = blockIdx.x * 256 + threadIdx.x;
  int tot = 5 * Opad * CP;
  if (idx >= tot) return;
  int seg = idx / (Opad * CP);
  int rem = idx - seg * (Opad * CP);
  int o = rem / CP, c = rem - (rem / CP) * CP;
  float v = 0.f;
  if (c < C && o < O) {
    const int blkmap[5] = {0, 1, 2, 4, 5};
    int blk = blkmap[seg];
    v = W[(blk * C + c) * O + o];
    if (seg == 0) v += W[(3 * C + c) * O + o];
  }
  WT[idx] = __float2bfloat16(v);
}

// ---- merged builds: one coalesced pass -> XT (c-major) + XC (r-major, padded) ----
// block = (ntile in [0,8), b in [0,64)); 64 n per block; LDS transpose tile.
__global__ __launch_bounds__(256) void build_enc2(
    bf16* __restrict__ XT, bf16* __restrict__ XC, const float* __restrict__ x,
    const float* __restrict__ HT, const float* __restrict__ ZRT, int t) {
  __shared__ bf16 T[65][66];
  const int n0 = blockIdx.x * 64, b = blockIdx.y, tid = threadIdx.x;
  for (int e = tid; e < 65 * 64; e += 256) {
    int c = e >> 6, j = e & 63;
    int n = n0 + j, r = b * 512 + n;
    float v;
    if (c == 0) v = x[b * 6144 + n * 12 + t];
    else {
      v = HT[(size_t)(c - 1) * NB + r];
      if (ZRT) v *= ZRT[(size_t)(c - 1) * NB + r];
    }
    bf16 bv = __float2bfloat16(v);
    T[c][j] = bv;
    XT[((size_t)b * 65 + c) * 512 + n] = bv;
  }
  __syncthreads();
  const bf16 z = __float2bfloat16(0.f);
  for (int e = tid; e < 64 * 48; e += 256) {         // CP=96 -> 48 u32 per row
    int j = e / 48, p = e - j * 48;
    int c0 = 2 * p;
    int r = b * 512 + n0 + j;
    union { unsigned u; bf16 h[2]; } w;
    w.h[0] = (c0 < 65) ? T[c0][j] : z;
    w.h[1] = (c0 + 1 < 65) ? T[c0 + 1][j] : z;
    *(unsigned*)(XC + (size_t)r * 96 + c0) = w.u;
  }
}

__global__ __launch_bounds__(256) void build_dec2(
    bf16* __restrict__ XT, bf16* __restrict__ XC, const float* __restrict__ GO,
    const float* __restrict__ tt, const float* __restrict__ HT,
    const float* __restrict__ ZRT, int t) {
  __shared__ bf16 T[134][66];
  const int n0 = blockIdx.x * 64, b = blockIdx.y, tid = threadIdx.x;
  for (int e = tid; e < 134 * 64; e += 256) {
    int c = e >> 6, j = e & 63;
    int n = n0 + j, r = b * 512 + n;
    float v;
    if (c == 0) v = GO[r];
    else if (c < 6) v = tt[b * 60 + (c - 1) * 12 + t];
    else {
      v = HT[(size_t)(c - 6) * NB + r];
      if (ZRT) v *= ZRT[(size_t)(c - 6) * NB + r];
    }
    bf16 bv = __float2bfloat16(v);
    T[c][j] = bv;
    XT[((size_t)b * 134 + c) * 512 + n] = bv;
  }
  __syncthreads();
  const bf16 z = __float2bfloat16(0.f);
  for (int e = tid; e < 64 * 80; e += 256) {         // CP=160 -> 80 u32 per row
    int j = e / 80, p = e - j * 80;
    int c0 = 2 * p;
    int r = b * 512 + n0 + j;
    union { unsigned u; bf16 h[2]; } w;
    w.h[0] = (c0 < 134) ? T[c0][j] : z;
    w.h[1] = (c0 + 1 < 134) ? T[c0 + 1][j] : z;
    *(unsigned*)(XC + (size_t)r * 160 + c0) = w.u;
  }
}

__global__ __launch_bounds__(64)
void attention(const float* __restrict__ HbT, const float* __restrict__ Wq,
               const float* __restrict__ Mem, float* __restrict__ HdT) {
  int r = blockIdx.x, t = threadIdx.x;
  __shared__ float hrow[RNN], q[MEMD], sc[MEMN];
  hrow[t] = HbT[(size_t)t * NB + r];
  __syncthreads();
  float a = 0.f;
  for (int k = 0; k < RNN; k++) a += hrow[k] * Wq[k * MEMD + t];
  q[t] = a;
  __syncthreads();
  if (t < MEMN) {
    float s = 0.f;
    for (int c = 0; c < MEMD; c++) s += q[c] * Mem[t * MEMD + c];
    sc[t] = s;
  }
  __syncthreads();
  if (t == 0) {
    float m = -1e30f;
    for (int j = 0; j < MEMN; j++) m = fmaxf(m, sc[j]);
    float ssum = 0.f;
    for (int j = 0; j < MEMN; j++) { sc[j] = expf(sc[j] - m); ssum += sc[j]; }
    float inv = 1.f / ssum;
    for (int j = 0; j < MEMN; j++) sc[j] *= inv;
  }
  __syncthreads();
  float ha = 0.f;
  for (int j = 0; j < MEMN; j++) ha += sc[j] * Mem[j * MEMD + t];
  HdT[(size_t)t * NB + r] = hrow[t];
  HdT[(size_t)(RNN + t) * NB + r] = ha;
}

__global__ void dec_out(const float* __restrict__ HdT, const float* __restrict__ pW,
                        const float* __restrict__ pb, float* __restrict__ out,
                        float* __restrict__ GO, int t) {
  int r = blockIdx.x * 256 + threadIdx.x;
  if (r >= NB) return;
  float s = pb[0];
  for (int c = 0; c < DD; c++) s += HdT[(size_t)c * NB + r] * pW[c];
  GO[r] = s;
  int b = r >> 9, n = r & 511;
  out[b * 6144 + n * 12 + t] = s;
}

// ---------------- host ----------------
extern "C" void kernel_launch(void* const* d_in, const int* in_sizes, int n_in,
                              void* d_out, int out_size, void* d_ws, size_t ws_size,
                              hipStream_t stream) {
  const float* x   = (const float*)d_in[0];
  const float* tt  = (const float*)d_in[3];
  const float* Mem = (const float*)d_in[5];
  const float* Wq  = (const float*)d_in[6];
  const float* We1 = (const float*)d_in[7];
  const float* We2 = (const float*)d_in[8];
  const float* egW = (const float*)d_in[9];
  const float* egb = (const float*)d_in[10];
  const float* euW = (const float*)d_in[11];
  const float* eub = (const float*)d_in[12];
  const float* dgW = (const float*)d_in[13];
  const float* dgb = (const float*)d_in[14];
  const float* duW = (const float*)d_in[15];
  const float* dub = (const float*)d_in[16];
  const float* pW  = (const float*)d_in[17];
  const float* pb  = (const float*)d_in[18];
  float* out = (float*)d_out;

  char* ws = (char*)d_ws;
  size_t off = 0;
  auto alloc = [&](size_t bytes) { char* p = ws + off; off += (bytes + 255) & ~(size_t)255; return p; };
  // ---- zeroed-at-launch-start region (contiguous) ----
  bf16* Ybuf  = (bf16*)alloc((size_t)4 * NB * 160 * 2);    // [s][r*CP + c]
  float* HbT  = (float*)alloc((size_t)RNN * NB * 4);       // [o][r]
  float* GO   = (float*)alloc((size_t)NB * 4);
  size_t zero_bytes = off;
  // ---- rest ----
  bf16* XC    = (bf16*)alloc((size_t)NB * 160 * 2);        // [r*CP + c] (pads built-in)
  bf16* WTeg  = (bf16*)alloc((size_t)5 * 128 * 96 * 2);
  bf16* WTeu  = (bf16*)alloc((size_t)5 * 128 * 96 * 2);
  bf16* WTdg  = (bf16*)alloc((size_t)5 * 256 * 160 * 2);
  bf16* WTdu  = (bf16*)alloc((size_t)5 * 128 * 160 * 2);
  bf16* XT    = (bf16*)alloc((size_t)8576 * 512 * 2);      // [(b*C+c)][n]
  bf16* Sb    = (bf16*)alloc((size_t)4 * 512 * 512 * 2);
  bf16* g1T   = (bf16*)alloc((size_t)512 * 512 * 2);
  bf16* g2T   = (bf16*)alloc((size_t)512 * 512 * 2);
  float* ZRT  = (float*)alloc((size_t)256 * NB * 4);       // [o][r]
  float* HdT  = (float*)alloc((size_t)DD * NB * 4);
  float* e1   = (float*)alloc((size_t)N_ * MEMD * 4);
  float* e2   = (float*)alloc((size_t)N_ * MEMD * 4);
  float* S    = (float*)alloc((size_t)N_ * N_ * 4);
  float* ST   = (float*)alloc((size_t)N_ * N_ * 4);
  float* g1f  = (float*)alloc((size_t)N_ * N_ * 4);
  float* g2f  = (float*)alloc((size_t)N_ * N_ * 4);

  auto blk = [](long n) { return dim3((unsigned)((n + 255) / 256)); };

  // ---- phase 0 ----
  fill_zero4<<<2048, 256, 0, stream>>>((float4*)ws, (int)(zero_bytes / 16));
  compute_e<<<blk(N_ * MEMD), 256, 0, stream>>>(We1, We2, Mem, e1, e2);
  scores_relu<<<blk(N_ * N_), 256, 0, stream>>>(e1, e2, S);
  trans_f32<<<dim3(16, 16), dim3(32, 8), 0, stream>>>(S, ST);
  row_softmax<<<N_, 256, 0, stream>>>(S, g1f);
  row_softmax<<<N_, 256, 0, stream>>>(ST, g2f);
  trans_to_bf16<<<dim3(16, 16), dim3(32, 8), 0, stream>>>(g1f, Sb + 0 * 262144, g1T);
  trans_to_bf16<<<dim3(16, 16), dim3(32, 8), 0, stream>>>(g2f, Sb + 2 * 262144, g2T);
  gemm_cheb<<<dim3(4, 4), 256, 0, stream>>>(Sb + 0 * 262144, g1T, Sb + 1 * 262144);
  gemm_cheb<<<dim3(4, 4), 256, 0, stream>>>(Sb + 2 * 262144, g2T, Sb + 3 * 262144);
  prep_wt<<<blk(5 * 128 * 96), 256, 0, stream>>>(egW, WTeg, 65, 128, 128, 96);
  prep_wt<<<blk(5 * 128 * 96), 256, 0, stream>>>(euW, WTeu, 65, 64, 128, 96);
  prep_wt<<<blk(5 * 256 * 160), 256, 0, stream>>>(dgW, WTdg, 134, 256, 256, 160);
  prep_wt<<<blk(5 * 128 * 160), 256, 0, stream>>>(duW, WTdu, 134, 128, 128, 160);

  // ---- encoder ----
  for (int t = 0; t < L_; t++) {
    build_enc2<<<dim3(8, 64), 256, 0, stream>>>(XT, XC, x, HbT, nullptr, t);
    gemm_mix<65, 96><<<dim3(33, 16), 256, 0, stream>>>(Sb, XT, Ybuf);
    gemm_proj<96, 0><<<dim3(256, 1), 256, 0, stream>>>(WTeg, XC, Ybuf, egb, ZRT, nullptr, RNN);
    build_enc2<<<dim3(8, 64), 256, 0, stream>>>(XT, XC, x, HbT, ZRT, t);
    gemm_mix<65, 96><<<dim3(33, 16), 256, 0, stream>>>(Sb, XT, Ybuf);
    gemm_proj<96, 1><<<dim3(256, 1), 256, 0, stream>>>(WTeu, XC, Ybuf, eub, ZRT, HbT, RNN);
  }

  // ---- attention -> HdT ; dec-stride pads ----
  attention<<<dim3(NB), 64, 0, stream>>>(HbT, Wq, Mem, HdT);
  fill_ybuf_pads<<<blk((long)4 * NB * 26), 256, 0, stream>>>(Ybuf);

  // ---- decoder ----
  for (int t = 0; t < H_; t++) {
    build_dec2<<<dim3(8, 64), 256, 0, stream>>>(XT, XC, GO, tt, HdT, nullptr, t);
    gemm_mix<134, 160><<<dim3(67, 16), 256, 0, stream>>>(Sb, XT, Ybuf);
    gemm_proj<160, 0><<<dim3(256, 2), 256, 0, stream>>>(WTdg, XC, Ybuf, dgb, ZRT, nullptr, DD);
    build_dec2<<<dim3(8, 64), 256, 0, stream>>>(XT, XC, GO, tt, HdT, ZRT, t);
    gemm_mix<134, 160><<<dim3(67, 16), 256, 0, stream>>>(Sb, XT, Ybuf);
    gemm_proj<160, 1><<<dim3(256, 1), 256, 0, stream>>>(WTdu, XC, Ybuf, dub, ZRT, HdT, DD);
    dec_out<<<blk(NB), 256, 0, stream>>>(HdT, pW, pb, out, GO, t);
  }
}